// Round 1
// baseline (1974.679 us; speedup 1.0000x reference)
//
#include <hip/hip_runtime.h>

constexpr int B  = 16;
constexpr int S  = 128;
constexpr int NC = 100;
constexpr int DK = 128;
constexpr int T  = S - 1;       // 127 scan steps
constexpr int HP = DK + 4;      // padded LDS row stride for h (bank-conflict fix)

__device__ __forceinline__ float sigm(float x)      { return 1.0f / (1.0f + __expf(-x)); }
__device__ __forceinline__ float tanh_fast(float x) { return 2.0f / (1.0f + __expf(-2.0f * x)) - 1.0f; }

// ---------------------------------------------------------------------------
// Kernel 1: AL[b,s,:] = [e_emb, at_emb, corr] @ W1 + b1
// grid = B*S blocks, 128 threads. Thread j computes output dim j.
// ---------------------------------------------------------------------------
__global__ void k_all_learning(const int* __restrict__ qs, const int* __restrict__ ats,
                               const float* __restrict__ corr,
                               const float* __restrict__ e_w, const float* __restrict__ at_w,
                               const float* __restrict__ W1, const float* __restrict__ b1,
                               float* __restrict__ AL) {
  int bs = blockIdx.x;
  int j  = threadIdx.x;
  __shared__ float v[3 * DK];
  int q = qs[bs], a = ats[bs];
  float c = corr[bs];
  v[j]          = e_w[q * DK + j];
  v[DK + j]     = at_w[a * DK + j];
  v[2 * DK + j] = c;
  __syncthreads();
  float acc = b1[j];
#pragma unroll 8
  for (int k = 0; k < 3 * DK; ++k) acc = fmaf(v[k], W1[k * DK + j], acc);
  AL[bs * DK + j] = acc;
}

// ---------------------------------------------------------------------------
// Kernel 2: per (b,t), t in [0,T):
//   K2 = learning_pre@W2a + it@W2b + learning@W2c + b2      (x4@W2 minus h_tilde part)
//   K3 = same with W3
//   C4 = it@W4c + b4                                        (gamma_f input minus h,LG parts)
//   C5 = e_next@W5a + b5                                    (y input minus h_tilde part)
// grid = B*T blocks, 128 threads.
// ---------------------------------------------------------------------------
__global__ void k_consts(const int* __restrict__ qs, const int* __restrict__ its,
                         const float* __restrict__ it_w, const float* __restrict__ e_w,
                         const float* __restrict__ AL,
                         const float* __restrict__ W2, const float* __restrict__ b2,
                         const float* __restrict__ W3, const float* __restrict__ b3,
                         const float* __restrict__ W4, const float* __restrict__ b4,
                         const float* __restrict__ W5, const float* __restrict__ b5,
                         float* __restrict__ K2, float* __restrict__ K3,
                         float* __restrict__ C4, float* __restrict__ C5) {
  int blk = blockIdx.x;
  int b = blk / T, t = blk % T;
  int j  = threadIdx.x;
  int bs = b * S + t;
  __shared__ float lp[DK], itv[DK], lc[DK], en[DK];
  lp[j]  = (t == 0) ? 0.0f : AL[(bs - 1) * DK + j];
  lc[j]  = AL[bs * DK + j];
  itv[j] = it_w[its[bs] * DK + j];
  en[j]  = e_w[qs[bs + 1] * DK + j];
  __syncthreads();
  float a2 = b2[j], a3 = b3[j], a4 = b4[j], a5 = b5[j];
#pragma unroll 4
  for (int k = 0; k < DK; ++k) {
    float vlp = lp[k], vit = itv[k], vlc = lc[k], ven = en[k];
    a2 = fmaf(vlp, W2[k * DK + j], a2);
    a2 = fmaf(vit, W2[(DK + k) * DK + j], a2);
    a2 = fmaf(vlc, W2[(2 * DK + k) * DK + j], a2);
    a3 = fmaf(vlp, W3[k * DK + j], a3);
    a3 = fmaf(vit, W3[(DK + k) * DK + j], a3);
    a3 = fmaf(vlc, W3[(2 * DK + k) * DK + j], a3);
    a4 = fmaf(vit, W4[(2 * DK + k) * DK + j], a4);
    a5 = fmaf(ven, W5[k * DK + j], a5);
  }
  int o = (b * T + t) * DK + j;
  K2[o] = a2; K3[o] = a3; C4[o] = a4; C5[o] = a5;
}

// ---------------------------------------------------------------------------
// Kernel 3: the sequential scan. One block per batch element, 512 threads.
// h[100][128] (padded stride 132) lives in LDS for all 127 steps.
// ---------------------------------------------------------------------------
__global__ __launch_bounds__(512, 1)
void k_scan(const int* __restrict__ qs,
            const float* __restrict__ qmat,
            const float* __restrict__ h0,
            const float* __restrict__ K2, const float* __restrict__ K3,
            const float* __restrict__ C4, const float* __restrict__ C5,
            const float* __restrict__ W2, const float* __restrict__ W3,
            const float* __restrict__ W4, const float* __restrict__ W5,
            float* __restrict__ out) {
  const int b   = blockIdx.x;
  const int tid = threadIdx.x;

  __shared__ float h[NC * HP];     // padded: h[n*HP + k]
  __shared__ float sHT[DK];        // h_tilde (carry)
  __shared__ float sLG[DK];        // LG
  __shared__ float sV[DK];         // lg4 = C4 + LG@W4b
  __shared__ float sQE[NC];        // q_e  (current row of q_matrix)
  __shared__ float sQN[NC];        // q_next
  __shared__ float redA[4][DK];
  __shared__ float redB[4][DK];

  const float* W2d = W2 + 3 * DK * DK;  // h_tilde_pre rows of W2
  const float* W3d = W3 + 3 * DK * DK;
  const float* W4a = W4;                // h rows
  const float* W4b = W4 + DK * DK;      // LG rows
  const float* W5b = W5 + DK * DK;      // h_tilde rows

  // init h from shared h0
  for (int i = tid; i < NC * DK; i += 512) {
    int n = i / DK, k = i - n * DK;
    h[n * HP + k] = h0[i];
  }
  if (tid < NC) sQE[tid] = qmat[qs[b * S] * NC + tid];
  if (tid == 0) out[b * S] = 0.0f;
  __syncthreads();

  const int j  = tid & (DK - 1);
  const int r  = tid >> 7;          // 0..3   (K-split for GEMV phases)
  const int jt = tid >> 4;          // 0..31  (main GEMM: 4 output cols each)
  const int nt = tid & 15;          // 0..15  (main GEMM: rows n = nt+16*i)
  const int j4 = jt * 4;

  // h_tilde0 = q_e . h0
  {
    float p = 0.0f;
    for (int i = r * 25; i < r * 25 + 25; ++i) p = fmaf(sQE[i], h[i * HP + j], p);
    redA[r][j] = p;
    __syncthreads();
    if (tid < DK) sHT[tid] = redA[0][tid] + redA[1][tid] + redA[2][tid] + redA[3][tid];
    __syncthreads();
  }

  for (int t = 0; t < T; ++t) {
    // stage q_next (sQE holds row for current t)
    if (tid < NC) sQN[tid] = qmat[qs[b * S + t + 1] * NC + tid];

    // ---- phase A1: x2 = K2 + h_tilde@W2d ; x3 = K3 + h_tilde@W3d ; -> LG ----
    {
      float p2 = 0.0f, p3 = 0.0f;
      int k0 = r * 32;
#pragma unroll
      for (int kk = 0; kk < 32; ++kk) {
        float hv = sHT[k0 + kk];
        p2 = fmaf(hv, W2d[(k0 + kk) * DK + j], p2);
        p3 = fmaf(hv, W3d[(k0 + kk) * DK + j], p3);
      }
      redA[r][j] = p2;
      redB[r][j] = p3;
    }
    __syncthreads();
    if (tid < DK) {
      int o = (b * T + t) * DK + tid;
      float x2 = K2[o] + redA[0][tid] + redA[1][tid] + redA[2][tid] + redA[3][tid];
      float x3 = K3[o] + redB[0][tid] + redB[1][tid] + redB[2][tid] + redB[3][tid];
      float lg = tanh_fast(x2);
      float gl = sigm(x3);
      sLG[tid] = gl * (lg + 1.0f) * 0.5f;
    }
    __syncthreads();

    // ---- phase A2: lg4 = C4 + LG@W4b ----
    {
      float p = 0.0f;
      int k0 = r * 32;
#pragma unroll
      for (int kk = 0; kk < 32; ++kk) p = fmaf(sLG[k0 + kk], W4b[(k0 + kk) * DK + j], p);
      redA[r][j] = p;
    }
    __syncthreads();
    if (tid < DK)
      sV[tid] = C4[(b * T + t) * DK + tid] + redA[0][tid] + redA[1][tid] + redA[2][tid] + redA[3][tid];
    __syncthreads();

    // ---- phase B: dot = h @ W4a  (per thread: 4 cols j4..j4+3, rows nt+16i) ----
    float acc[7][4];
#pragma unroll
    for (int i = 0; i < 7; ++i)
#pragma unroll
      for (int c = 0; c < 4; ++c) acc[i][c] = 0.0f;

    for (int k4 = 0; k4 < DK; k4 += 4) {
      float4 w0 = *(const float4*)&W4a[(k4 + 0) * DK + j4];
      float4 w1 = *(const float4*)&W4a[(k4 + 1) * DK + j4];
      float4 w2 = *(const float4*)&W4a[(k4 + 2) * DK + j4];
      float4 w3 = *(const float4*)&W4a[(k4 + 3) * DK + j4];
#pragma unroll
      for (int i = 0; i < 7; ++i) {
        int n = nt + 16 * i;
        if (n < NC) {
          float4 hv = *(const float4*)&h[n * HP + k4];
          acc[i][0] = fmaf(hv.x, w0.x, acc[i][0]); acc[i][0] = fmaf(hv.y, w1.x, acc[i][0]);
          acc[i][0] = fmaf(hv.z, w2.x, acc[i][0]); acc[i][0] = fmaf(hv.w, w3.x, acc[i][0]);
          acc[i][1] = fmaf(hv.x, w0.y, acc[i][1]); acc[i][1] = fmaf(hv.y, w1.y, acc[i][1]);
          acc[i][1] = fmaf(hv.z, w2.y, acc[i][1]); acc[i][1] = fmaf(hv.w, w3.y, acc[i][1]);
          acc[i][2] = fmaf(hv.x, w0.z, acc[i][2]); acc[i][2] = fmaf(hv.y, w1.z, acc[i][2]);
          acc[i][2] = fmaf(hv.z, w2.z, acc[i][2]); acc[i][2] = fmaf(hv.w, w3.z, acc[i][2]);
          acc[i][3] = fmaf(hv.x, w0.w, acc[i][3]); acc[i][3] = fmaf(hv.y, w1.w, acc[i][3]);
          acc[i][3] = fmaf(hv.z, w2.w, acc[i][3]); acc[i][3] = fmaf(hv.w, w3.w, acc[i][3]);
        }
      }
    }
    __syncthreads();   // all reads of old h complete before updates

    // ---- phase B2: gamma_f, h update, h_tilde partials ----
    float pHT[4] = {0.f, 0.f, 0.f, 0.f};
#pragma unroll
    for (int i = 0; i < 7; ++i) {
      int n = nt + 16 * i;
      if (n < NC) {
        float qe = sQE[n], qn = sQN[n];
        float4 hv = *(float4*)&h[n * HP + j4];
        float hn0, hn1, hn2, hn3;
        {
          float gf = sigm(acc[i][0] + sV[j4 + 0]);
          hn0 = fmaf(gf, hv.x, qe * sLG[j4 + 0]);
          pHT[0] = fmaf(qn, hn0, pHT[0]);
        }
        {
          float gf = sigm(acc[i][1] + sV[j4 + 1]);
          hn1 = fmaf(gf, hv.y, qe * sLG[j4 + 1]);
          pHT[1] = fmaf(qn, hn1, pHT[1]);
        }
        {
          float gf = sigm(acc[i][2] + sV[j4 + 2]);
          hn2 = fmaf(gf, hv.z, qe * sLG[j4 + 2]);
          pHT[2] = fmaf(qn, hn2, pHT[2]);
        }
        {
          float gf = sigm(acc[i][3] + sV[j4 + 3]);
          hn3 = fmaf(gf, hv.w, qe * sLG[j4 + 3]);
          pHT[3] = fmaf(qn, hn3, pHT[3]);
        }
        float4 hw; hw.x = hn0; hw.y = hn1; hw.z = hn2; hw.w = hn3;
        *(float4*)&h[n * HP + j4] = hw;
      }
    }
    // reduce h_tilde partials over the 16 nt lanes (in-wave)
#pragma unroll
    for (int m = 1; m < 16; m <<= 1) {
#pragma unroll
      for (int c = 0; c < 4; ++c) pHT[c] += __shfl_xor(pHT[c], m, 64);
    }
    if (nt == 0) {
#pragma unroll
      for (int c = 0; c < 4; ++c) sHT[j4 + c] = pHT[c];
    }
    __syncthreads();   // new h_tilde + new h visible

    // ---- phase C: y = mean(sigmoid(C5 + h_tilde@W5b)) ----
    {
      float p = 0.0f;
      int k0 = r * 32;
#pragma unroll
      for (int kk = 0; kk < 32; ++kk) p = fmaf(sHT[k0 + kk], W5b[(k0 + kk) * DK + j], p);
      redA[r][j] = p;
    }
    __syncthreads();
    if (tid < DK) {
      float v = C5[(b * T + t) * DK + tid] + redA[0][tid] + redA[1][tid] + redA[2][tid] + redA[3][tid];
      redB[0][tid] = sigm(v);
    }
    __syncthreads();
    if (tid < 64) {
      float sacc = redB[0][tid] + redB[0][tid + 64];
#pragma unroll
      for (int m = 32; m >= 1; m >>= 1) sacc += __shfl_xor(sacc, m, 64);
      if (tid == 0) out[b * S + t + 1] = sacc * (1.0f / DK);
    }
    __syncthreads();
    if (tid < NC) sQE[tid] = sQN[tid];   // q_next becomes q_e
    __syncthreads();
  }
}

extern "C" void kernel_launch(void* const* d_in, const int* in_sizes, int n_in,
                              void* d_out, int out_size, void* d_ws, size_t ws_size,
                              hipStream_t stream) {
  const int*   qs   = (const int*)d_in[0];
  const int*   ats  = (const int*)d_in[1];
  const int*   its  = (const int*)d_in[2];
  const float* corr = (const float*)d_in[3];
  const float* qmat = (const float*)d_in[4];
  const float* h0   = (const float*)d_in[5];
  const float* e_w  = (const float*)d_in[6];
  const float* at_w = (const float*)d_in[7];
  const float* it_w = (const float*)d_in[8];
  const float* W1 = (const float*)d_in[9];  const float* b1 = (const float*)d_in[10];
  const float* W2 = (const float*)d_in[11]; const float* b2 = (const float*)d_in[12];
  const float* W3 = (const float*)d_in[13]; const float* b3 = (const float*)d_in[14];
  const float* W4 = (const float*)d_in[15]; const float* b4 = (const float*)d_in[16];
  const float* W5 = (const float*)d_in[17]; const float* b5 = (const float*)d_in[18];
  float* out = (float*)d_out;

  float* AL = (float*)d_ws;              // B*S*DK
  float* K2 = AL + B * S * DK;           // B*T*DK
  float* K3 = K2 + B * T * DK;
  float* C4 = K3 + B * T * DK;
  float* C5 = C4 + B * T * DK;

  k_all_learning<<<dim3(B * S), dim3(DK), 0, stream>>>(qs, ats, corr, e_w, at_w, W1, b1, AL);
  k_consts<<<dim3(B * T), dim3(DK), 0, stream>>>(qs, its, it_w, e_w, AL,
                                                 W2, b2, W3, b3, W4, b4, W5, b5,
                                                 K2, K3, C4, C5);
  k_scan<<<dim3(B), dim3(512), 0, stream>>>(qs, qmat, h0, K2, K3, C4, C5,
                                            W2, W3, W4, W5, out);
}

// Round 2
// 1064.775 us; speedup vs baseline: 1.8546x; 1.8546x over previous
//
#include <hip/hip_runtime.h>

constexpr int B  = 16;
constexpr int S  = 128;
constexpr int NC = 100;
constexpr int DK = 128;
constexpr int T  = S - 1;       // 127 scan steps

typedef __attribute__((ext_vector_type(8))) short bf16x8;
typedef __attribute__((ext_vector_type(4))) float f32x4;

__device__ __forceinline__ float sigm(float x) {
  return __builtin_amdgcn_rcpf(1.0f + __expf(-x));
}
__device__ __forceinline__ float tanh_fast(float x) {
  return 2.0f * __builtin_amdgcn_rcpf(1.0f + __expf(-2.0f * x)) - 1.0f;
}
__device__ __forceinline__ unsigned short f2bf(float x) {   // RNE f32 -> bf16
  unsigned u = __float_as_uint(x);
  u += 0x7fff + ((u >> 16) & 1);
  return (unsigned short)(u >> 16);
}

// ---------------------------------------------------------------------------
// Kernel 1: AL[b,s,:] = [e_emb, at_emb, corr] @ W1 + b1
// grid = B*16 blocks (8 s-values per block), 128 threads. W1 read once per 8 s.
// ---------------------------------------------------------------------------
__global__ void k_all_learning(const int* __restrict__ qs, const int* __restrict__ ats,
                               const float* __restrict__ corr,
                               const float* __restrict__ e_w, const float* __restrict__ at_w,
                               const float* __restrict__ W1, const float* __restrict__ b1,
                               float* __restrict__ AL) {
  int b = blockIdx.x >> 4, c = blockIdx.x & 15;
  int s0 = c * 8;
  int j = threadIdx.x;
  __shared__ float ve[8][DK], va[8][DK];
  __shared__ float cr[8];
#pragma unroll
  for (int i = 0; i < 8; ++i) {
    int bs = b * S + s0 + i;
    ve[i][j] = e_w[qs[bs] * DK + j];
    va[i][j] = at_w[ats[bs] * DK + j];
    if (j == 0) cr[i] = corr[bs];
  }
  __syncthreads();
  float acc[8];
  // corr part: corr is constant over k -> corr * colsum(W1 rows [2DK,3DK))
  float cs = 0.0f;
#pragma unroll 4
  for (int k = 0; k < DK; ++k) cs += W1[(2 * DK + k) * DK + j];
  float bj = b1[j];
#pragma unroll
  for (int i = 0; i < 8; ++i) acc[i] = bj + cr[i] * cs;
#pragma unroll 2
  for (int k = 0; k < DK; ++k) {
    float we = W1[k * DK + j];
    float wa = W1[(DK + k) * DK + j];
#pragma unroll
    for (int i = 0; i < 8; ++i) {
      acc[i] = fmaf(ve[i][k], we, acc[i]);
      acc[i] = fmaf(va[i][k], wa, acc[i]);
    }
  }
#pragma unroll
  for (int i = 0; i < 8; ++i) AL[(b * S + s0 + i) * DK + j] = acc[i];
}

// ---------------------------------------------------------------------------
// Kernel 2: per (b,t): K2/K3 (x4@W2/W3 minus h_tilde part), C4 (it@W4c+b4),
// C5 (e_next@W5a+b5). 8 t-values per block so W reads amortize 8x.
// ---------------------------------------------------------------------------
__global__ void k_consts(const int* __restrict__ qs, const int* __restrict__ its,
                         const float* __restrict__ it_w, const float* __restrict__ e_w,
                         const float* __restrict__ AL,
                         const float* __restrict__ W2, const float* __restrict__ b2,
                         const float* __restrict__ W3, const float* __restrict__ b3,
                         const float* __restrict__ W4, const float* __restrict__ b4,
                         const float* __restrict__ W5, const float* __restrict__ b5,
                         float* __restrict__ K2, float* __restrict__ K3,
                         float* __restrict__ C4, float* __restrict__ C5) {
  int b = blockIdx.x >> 4, c = blockIdx.x & 15;
  int t0 = c * 8;
  int nt = (t0 + 8 <= T) ? 8 : (T - t0);
  int j = threadIdx.x;
  __shared__ float lp[8][DK], itv[8][DK], lc[8][DK], en[8][DK];
  for (int i = 0; i < nt; ++i) {
    int bs = b * S + t0 + i;
    lp[i][j]  = (t0 + i == 0) ? 0.0f : AL[(bs - 1) * DK + j];
    lc[i][j]  = AL[bs * DK + j];
    itv[i][j] = it_w[its[bs] * DK + j];
    en[i][j]  = e_w[qs[bs + 1] * DK + j];
  }
  __syncthreads();
  float a2[8], a3[8], a4[8], a5[8];
  float v2 = b2[j], v3 = b3[j], v4 = b4[j], v5 = b5[j];
#pragma unroll
  for (int i = 0; i < 8; ++i) { a2[i] = v2; a3[i] = v3; a4[i] = v4; a5[i] = v5; }
#pragma unroll 2
  for (int k = 0; k < DK; ++k) {
    float w2a = W2[k * DK + j], w2b = W2[(DK + k) * DK + j], w2c = W2[(2 * DK + k) * DK + j];
    float w3a = W3[k * DK + j], w3b = W3[(DK + k) * DK + j], w3c = W3[(2 * DK + k) * DK + j];
    float w4c = W4[(2 * DK + k) * DK + j];
    float w5a = W5[k * DK + j];
#pragma unroll
    for (int i = 0; i < 8; ++i) {
      float vlp = lp[i][k], vit = itv[i][k], vlc = lc[i][k], ven = en[i][k];
      a2[i] = fmaf(vlp, w2a, a2[i]); a2[i] = fmaf(vit, w2b, a2[i]); a2[i] = fmaf(vlc, w2c, a2[i]);
      a3[i] = fmaf(vlp, w3a, a3[i]); a3[i] = fmaf(vit, w3b, a3[i]); a3[i] = fmaf(vlc, w3c, a3[i]);
      a4[i] = fmaf(vit, w4c, a4[i]);
      a5[i] = fmaf(ven, w5a, a5[i]);
    }
  }
  for (int i = 0; i < nt; ++i) {
    int o = (b * T + t0 + i) * DK + j;
    K2[o] = a2[i]; K3[o] = a3[i]; C4[o] = a4[i]; C5[o] = a5[i];
  }
}

// ---------------------------------------------------------------------------
// Kernel 3: sequential scan. 1 block/batch, 512 threads = 8 waves.
// dot = W4a^T (A, regs, bf16) x h^T (B, LDS bf16 hi+lo, XOR-swizzled) via MFMA.
// h (f32) + dot live in registers in the MFMA C-layout; B2 is register-only.
// Wave (wj=w&3, wn=w>>2): j-tiles {2wj,2wj+1}, n-tiles {4wn..4wn+3}.
// Lane: j = 16*jt_abs + 4*(l>>4) + reg ; n = 16*nt_abs + (l&15).
// ---------------------------------------------------------------------------
__global__ __launch_bounds__(512)
void k_scan(const int* __restrict__ qs,
            const float* __restrict__ qmat,
            const float* __restrict__ h0,
            const float* __restrict__ K2, const float* __restrict__ K3,
            const float* __restrict__ C4, const float* __restrict__ C5,
            const float* __restrict__ W2, const float* __restrict__ W3,
            const float* __restrict__ W4, const float* __restrict__ W5,
            float* __restrict__ out) {
  const int b   = blockIdx.x;
  const int tid = threadIdx.x;
  const int w   = tid >> 6;
  const int l   = tid & 63;
  const int l15 = l & 15;
  const int g   = l >> 4;          // 0..3
  const int wj  = w & 3;           // j-tile pair
  const int wn  = w >> 2;          // n-tile quad (0..1)
  const int gc  = 16 * w + l15;    // GEMV output column
  const int kb  = g * 32;          // GEMV k-base

  __shared__ unsigned short hH[DK * DK];   // h hi bf16, swizzled
  __shared__ unsigned short hL[DK * DK];   // h lo bf16, swizzled
  __shared__ float sHT[DK], sLG[DK], sV[DK];
  __shared__ float sHTp[2][DK];
  __shared__ float sQ[2][DK];
  __shared__ float sY[8];

  const float* W2d = W2 + 3 * DK * DK;
  const float* W3d = W3 + 3 * DK * DK;
  const float* W4a = W4;
  const float* W4b = W4 + DK * DK;
  const float* W5b = W5 + DK * DK;

  // ---- preload A-fragments: A = W4a^T, A[row=j][k] = W4a[k][j]
  bf16x8 afr[2][4];
#pragma unroll
  for (int jt = 0; jt < 2; ++jt) {
    int j = 16 * (2 * wj + jt) + l15;
#pragma unroll
    for (int ks = 0; ks < 4; ++ks) {
      bf16x8 v;
#pragma unroll
      for (int e = 0; e < 8; ++e) {
        int k = ks * 32 + g * 8 + e;
        v[e] = (short)f2bf(W4a[k * DK + j]);
      }
      afr[jt][ks] = v;
    }
  }

  if (tid < DK) sQ[0][tid] = (tid < NC) ? qmat[qs[b * S] * NC + tid] : 0.0f;
  if (tid == 0) out[b * S] = 0.0f;

  // ---- init h_old registers (C layout) + bf16 split into LDS
  float hold[2][4][4];
#pragma unroll
  for (int jt = 0; jt < 2; ++jt) {
    int j4 = 16 * (2 * wj + jt) + 4 * g;
#pragma unroll
    for (int nt = 0; nt < 4; ++nt) {
      int n = 16 * (4 * wn + nt) + l15;
      ushort4 vh, vl;
#pragma unroll
      for (int r = 0; r < 4; ++r) {
        float x = (n < NC) ? h0[n * DK + j4 + r] : 0.0f;
        hold[jt][nt][r] = x;
        unsigned short hi = f2bf(x);
        float fhi = __uint_as_float(((unsigned)hi) << 16);
        ((unsigned short*)&vh)[r] = hi;
        ((unsigned short*)&vl)[r] = f2bf(x - fhi);
      }
      int off = n * DK + (j4 ^ ((n & 7) << 3));
      *(ushort4*)&hH[off] = vh;
      *(ushort4*)&hL[off] = vl;
    }
  }
  __syncthreads();

  // ---- h_tilde0 = q_e(0) . h0  (same reduction path as B2)
  {
    float htp[2][4] = {};
#pragma unroll
    for (int jt = 0; jt < 2; ++jt)
#pragma unroll
      for (int nt = 0; nt < 4; ++nt) {
        int n = 16 * (4 * wn + nt) + l15;
        float qe = sQ[0][n];
#pragma unroll
        for (int r = 0; r < 4; ++r) htp[jt][r] = fmaf(qe, hold[jt][nt][r], htp[jt][r]);
      }
#pragma unroll
    for (int jt = 0; jt < 2; ++jt)
#pragma unroll
      for (int r = 0; r < 4; ++r) {
        float v = htp[jt][r];
        v += __shfl_xor(v, 1, 64); v += __shfl_xor(v, 2, 64);
        v += __shfl_xor(v, 4, 64); v += __shfl_xor(v, 8, 64);
        htp[jt][r] = v;
      }
    if (l15 == 0) {
#pragma unroll
      for (int jt = 0; jt < 2; ++jt)
#pragma unroll
        for (int r = 0; r < 4; ++r)
          sHTp[wn][16 * (2 * wj + jt) + 4 * g + r] = htp[jt][r];
    }
  }
  __syncthreads();
  if (tid < DK) sHT[tid] = sHTp[0][tid] + sHTp[1][tid];
  __syncthreads();

  for (int t = 0; t < T; ++t) {
    const int cur = t & 1, nxt = cur ^ 1;
    const int bt = (b * T + t) * DK;

    // stage q row t+1 (zero-padded to 128)
    if (tid < DK) sQ[nxt][tid] = (tid < NC) ? qmat[qs[b * S + t + 1] * NC + tid] : 0.0f;

    // ---- Phase M: dot = W4a^T x h^T  (2-term: h_hi + h_lo), reads prev-step h_bf
    f32x4 acc[2][4];
#pragma unroll
    for (int jt = 0; jt < 2; ++jt)
#pragma unroll
      for (int nt = 0; nt < 4; ++nt) acc[jt][nt] = (f32x4){0.f, 0.f, 0.f, 0.f};
#pragma unroll
    for (int nt = 0; nt < 4; ++nt) {
      int n  = 16 * (4 * wn + nt) + l15;
      int rb = n * DK;
      int xr = (n & 7) << 3;
      bf16x8 bh[4], bl[4];
#pragma unroll
      for (int ks = 0; ks < 4; ++ks) {
        int off = rb + ((ks * 32 + g * 8) ^ xr);
        bh[ks] = *(const bf16x8*)&hH[off];
        bl[ks] = *(const bf16x8*)&hL[off];
      }
#pragma unroll
      for (int jt = 0; jt < 2; ++jt)
#pragma unroll
        for (int ks = 0; ks < 4; ++ks) {
          acc[jt][nt] = __builtin_amdgcn_mfma_f32_16x16x32_bf16(afr[jt][ks], bh[ks], acc[jt][nt], 0, 0, 0);
          acc[jt][nt] = __builtin_amdgcn_mfma_f32_16x16x32_bf16(afr[jt][ks], bl[ks], acc[jt][nt], 0, 0, 0);
        }
    }

    // ---- Phase A1: x2/x3 = K2/K3 + h_tilde @ W2d/W3d -> LG (wave-GEMV)
    {
      float p2 = 0.f, p3 = 0.f;
#pragma unroll
      for (int kk = 0; kk < 32; ++kk) {
        float hv = sHT[kb + kk];
        p2 = fmaf(hv, W2d[(kb + kk) * DK + gc], p2);
        p3 = fmaf(hv, W3d[(kb + kk) * DK + gc], p3);
      }
      p2 += __shfl_xor(p2, 16, 64); p2 += __shfl_xor(p2, 32, 64);
      p3 += __shfl_xor(p3, 16, 64); p3 += __shfl_xor(p3, 32, 64);
      if (l < 16) {
        float x2 = K2[bt + gc] + p2;
        float x3 = K3[bt + gc] + p3;
        sLG[gc] = sigm(x3) * (tanh_fast(x2) + 1.0f) * 0.5f;
      }
    }
    __syncthreads();   // b1: sLG, sQ[nxt]

    // ---- Phase A2: V = C4 + LG @ W4b (wave-GEMV)
    {
      float pa = 0.f, pb = 0.f;
#pragma unroll
      for (int kk = 0; kk < 32; kk += 2) {
        pa = fmaf(sLG[kb + kk],     W4b[(kb + kk) * DK + gc],     pa);
        pb = fmaf(sLG[kb + kk + 1], W4b[(kb + kk + 1) * DK + gc], pb);
      }
      float p = pa + pb;
      p += __shfl_xor(p, 16, 64); p += __shfl_xor(p, 32, 64);
      if (l < 16) sV[gc] = C4[bt + gc] + p;
    }
    __syncthreads();   // b2: sV

    // ---- Phase B2: gamma_f, h update (registers), h_tilde partials, bf16 writeback
    {
      float lgv[2][4], vv[2][4], qev[4], qnv[4];
#pragma unroll
      for (int jt = 0; jt < 2; ++jt) {
        int j4 = 16 * (2 * wj + jt) + 4 * g;
        float4 a = *(const float4*)&sLG[j4];
        float4 c = *(const float4*)&sV[j4];
        lgv[jt][0] = a.x; lgv[jt][1] = a.y; lgv[jt][2] = a.z; lgv[jt][3] = a.w;
        vv[jt][0]  = c.x; vv[jt][1]  = c.y; vv[jt][2]  = c.z; vv[jt][3]  = c.w;
      }
#pragma unroll
      for (int nt = 0; nt < 4; ++nt) {
        int n = 16 * (4 * wn + nt) + l15;
        qev[nt] = sQ[cur][n];
        qnv[nt] = sQ[nxt][n];
      }
      float htp[2][4] = {};
#pragma unroll
      for (int jt = 0; jt < 2; ++jt) {
        int j4 = 16 * (2 * wj + jt) + 4 * g;
#pragma unroll
        for (int nt = 0; nt < 4; ++nt) {
          int n = 16 * (4 * wn + nt) + l15;
          ushort4 vh, vl;
#pragma unroll
          for (int r = 0; r < 4; ++r) {
            float gf = sigm(acc[jt][nt][r] + vv[jt][r]);
            float hn = fmaf(gf, hold[jt][nt][r], qev[nt] * lgv[jt][r]);
            hold[jt][nt][r] = hn;
            htp[jt][r] = fmaf(qnv[nt], hn, htp[jt][r]);
            unsigned short hi = f2bf(hn);
            ((unsigned short*)&vh)[r] = hi;
            ((unsigned short*)&vl)[r] = f2bf(hn - __uint_as_float(((unsigned)hi) << 16));
          }
          int off = n * DK + (j4 ^ ((n & 7) << 3));
          *(ushort4*)&hH[off] = vh;
          *(ushort4*)&hL[off] = vl;
        }
      }
#pragma unroll
      for (int jt = 0; jt < 2; ++jt)
#pragma unroll
        for (int r = 0; r < 4; ++r) {
          float v = htp[jt][r];
          v += __shfl_xor(v, 1, 64); v += __shfl_xor(v, 2, 64);
          v += __shfl_xor(v, 4, 64); v += __shfl_xor(v, 8, 64);
          htp[jt][r] = v;
        }
      if (l15 == 0) {
#pragma unroll
        for (int jt = 0; jt < 2; ++jt)
#pragma unroll
          for (int r = 0; r < 4; ++r)
            sHTp[wn][16 * (2 * wj + jt) + 4 * g + r] = htp[jt][r];
      }
    }
    __syncthreads();   // b3: sHTp (+ hH/hL for next step)
    if (tid < DK) sHT[tid] = sHTp[0][tid] + sHTp[1][tid];
    __syncthreads();   // b4: sHT

    // ---- Phase C: y = mean(sigmoid(C5 + h_tilde @ W5b))
    {
      float pa = 0.f, pb = 0.f;
#pragma unroll
      for (int kk = 0; kk < 32; kk += 2) {
        pa = fmaf(sHT[kb + kk],     W5b[(kb + kk) * DK + gc],     pa);
        pb = fmaf(sHT[kb + kk + 1], W5b[(kb + kk + 1) * DK + gc], pb);
      }
      float p = pa + pb;
      p += __shfl_xor(p, 16, 64); p += __shfl_xor(p, 32, 64);
      float u = sigm(C5[bt + gc] + p);
      u += __shfl_xor(u, 1, 64); u += __shfl_xor(u, 2, 64);
      u += __shfl_xor(u, 4, 64); u += __shfl_xor(u, 8, 64);
      if (l == 0) sY[w] = u;
    }
    __syncthreads();   // b5: sY
    if (tid == 0) {
      float s = 0.f;
#pragma unroll
      for (int i = 0; i < 8; ++i) s += sY[i];
      out[b * S + t + 1] = s * (1.0f / DK);
    }
  }
}

extern "C" void kernel_launch(void* const* d_in, const int* in_sizes, int n_in,
                              void* d_out, int out_size, void* d_ws, size_t ws_size,
                              hipStream_t stream) {
  const int*   qs   = (const int*)d_in[0];
  const int*   ats  = (const int*)d_in[1];
  const int*   its  = (const int*)d_in[2];
  const float* corr = (const float*)d_in[3];
  const float* qmat = (const float*)d_in[4];
  const float* h0   = (const float*)d_in[5];
  const float* e_w  = (const float*)d_in[6];
  const float* at_w = (const float*)d_in[7];
  const float* it_w = (const float*)d_in[8];
  const float* W1 = (const float*)d_in[9];  const float* b1 = (const float*)d_in[10];
  const float* W2 = (const float*)d_in[11]; const float* b2 = (const float*)d_in[12];
  const float* W3 = (const float*)d_in[13]; const float* b3 = (const float*)d_in[14];
  const float* W4 = (const float*)d_in[15]; const float* b4 = (const float*)d_in[16];
  const float* W5 = (const float*)d_in[17]; const float* b5 = (const float*)d_in[18];
  float* out = (float*)d_out;

  float* AL = (float*)d_ws;              // B*S*DK
  float* K2 = AL + B * S * DK;           // B*T*DK
  float* K3 = K2 + B * T * DK;
  float* C4 = K3 + B * T * DK;
  float* C5 = C4 + B * T * DK;

  k_all_learning<<<dim3(B * 16), dim3(DK), 0, stream>>>(qs, ats, corr, e_w, at_w, W1, b1, AL);
  k_consts<<<dim3(B * 16), dim3(DK), 0, stream>>>(qs, its, it_w, e_w, AL,
                                                  W2, b2, W3, b3, W4, b4, W5, b5,
                                                  K2, K3, C4, C5);
  k_scan<<<dim3(B), dim3(512), 0, stream>>>(qs, qmat, h0, K2, K3, C4, C5,
                                            W2, W3, W4, W5, out);
}

// Round 3
// 1009.345 us; speedup vs baseline: 1.9564x; 1.0549x over previous
//
#include <hip/hip_runtime.h>

constexpr int B  = 16;
constexpr int S  = 128;
constexpr int NC = 100;
constexpr int DK = 128;
constexpr int T  = S - 1;

typedef __attribute__((ext_vector_type(8))) short bf16x8;
typedef __attribute__((ext_vector_type(8))) unsigned short u16x8;
typedef __attribute__((ext_vector_type(4))) float f32x4;

__device__ __forceinline__ float sigm(float x) {
  return __builtin_amdgcn_rcpf(1.0f + __expf(-x));
}
__device__ __forceinline__ float tanh_fast(float x) {
  return 2.0f * __builtin_amdgcn_rcpf(1.0f + __expf(-2.0f * x)) - 1.0f;
}
__device__ __forceinline__ unsigned short f2bf(float x) {   // RNE f32 -> bf16
  unsigned u = __float_as_uint(x);
  u += 0x7fff + ((u >> 16) & 1);
  return (unsigned short)(u >> 16);
}
// padded index: +4 words after each 32-float chunk (breaks 128B bank aliasing)
__device__ __forceinline__ int pk(int k) { return k + ((k >> 5) << 2); }

// ---------------------------------------------------------------------------
// Kernel 1: AL[b,s,:] = [e_emb, at_emb, corr] @ W1 + b1   (8 s per block)
// ---------------------------------------------------------------------------
__global__ void k_all_learning(const int* __restrict__ qs, const int* __restrict__ ats,
                               const float* __restrict__ corr,
                               const float* __restrict__ e_w, const float* __restrict__ at_w,
                               const float* __restrict__ W1, const float* __restrict__ b1,
                               float* __restrict__ AL) {
  int b = blockIdx.x >> 4, c = blockIdx.x & 15;
  int s0 = c * 8;
  int j = threadIdx.x;
  __shared__ float ve[8][DK], va[8][DK];
  __shared__ float cr[8];
#pragma unroll
  for (int i = 0; i < 8; ++i) {
    int bs = b * S + s0 + i;
    ve[i][j] = e_w[qs[bs] * DK + j];
    va[i][j] = at_w[ats[bs] * DK + j];
    if (j == 0) cr[i] = corr[bs];
  }
  __syncthreads();
  float acc[8];
  float cs = 0.0f;
#pragma unroll 4
  for (int k = 0; k < DK; ++k) cs += W1[(2 * DK + k) * DK + j];
  float bj = b1[j];
#pragma unroll
  for (int i = 0; i < 8; ++i) acc[i] = bj + cr[i] * cs;
#pragma unroll 2
  for (int k = 0; k < DK; ++k) {
    float we = W1[k * DK + j];
    float wa = W1[(DK + k) * DK + j];
#pragma unroll
    for (int i = 0; i < 8; ++i) {
      acc[i] = fmaf(ve[i][k], we, acc[i]);
      acc[i] = fmaf(va[i][k], wa, acc[i]);
    }
  }
#pragma unroll
  for (int i = 0; i < 8; ++i) AL[(b * S + s0 + i) * DK + j] = acc[i];
}

// ---------------------------------------------------------------------------
// Kernel 2: per (b,t): K2/K3 (x4@W2/W3 minus h_tilde part), C4, C5.
// ---------------------------------------------------------------------------
__global__ void k_consts(const int* __restrict__ qs, const int* __restrict__ its,
                         const float* __restrict__ it_w, const float* __restrict__ e_w,
                         const float* __restrict__ AL,
                         const float* __restrict__ W2, const float* __restrict__ b2,
                         const float* __restrict__ W3, const float* __restrict__ b3,
                         const float* __restrict__ W4, const float* __restrict__ b4,
                         const float* __restrict__ W5, const float* __restrict__ b5,
                         float* __restrict__ K2, float* __restrict__ K3,
                         float* __restrict__ C4, float* __restrict__ C5) {
  int b = blockIdx.x >> 4, c = blockIdx.x & 15;
  int t0 = c * 8;
  int nt = (t0 + 8 <= T) ? 8 : (T - t0);
  int j = threadIdx.x;
  __shared__ float lp[8][DK], itv[8][DK], lc[8][DK], en[8][DK];
  for (int i = 0; i < nt; ++i) {
    int bs = b * S + t0 + i;
    lp[i][j]  = (t0 + i == 0) ? 0.0f : AL[(bs - 1) * DK + j];
    lc[i][j]  = AL[bs * DK + j];
    itv[i][j] = it_w[its[bs] * DK + j];
    en[i][j]  = e_w[qs[bs + 1] * DK + j];
  }
  __syncthreads();
  float a2[8], a3[8], a4[8], a5[8];
  float v2 = b2[j], v3 = b3[j], v4 = b4[j], v5 = b5[j];
#pragma unroll
  for (int i = 0; i < 8; ++i) { a2[i] = v2; a3[i] = v3; a4[i] = v4; a5[i] = v5; }
#pragma unroll 2
  for (int k = 0; k < DK; ++k) {
    float w2a = W2[k * DK + j], w2b = W2[(DK + k) * DK + j], w2c = W2[(2 * DK + k) * DK + j];
    float w3a = W3[k * DK + j], w3b = W3[(DK + k) * DK + j], w3c = W3[(2 * DK + k) * DK + j];
    float w4c = W4[(2 * DK + k) * DK + j];
    float w5a = W5[k * DK + j];
#pragma unroll
    for (int i = 0; i < 8; ++i) {
      float vlp = lp[i][k], vit = itv[i][k], vlc = lc[i][k], ven = en[i][k];
      a2[i] = fmaf(vlp, w2a, a2[i]); a2[i] = fmaf(vit, w2b, a2[i]); a2[i] = fmaf(vlc, w2c, a2[i]);
      a3[i] = fmaf(vlp, w3a, a3[i]); a3[i] = fmaf(vit, w3b, a3[i]); a3[i] = fmaf(vlc, w3c, a3[i]);
      a4[i] = fmaf(vit, w4c, a4[i]);
      a5[i] = fmaf(ven, w5a, a5[i]);
    }
  }
  for (int i = 0; i < nt; ++i) {
    int o = (b * T + t0 + i) * DK + j;
    K2[o] = a2[i]; K3[o] = a3[i]; C4[o] = a4[i]; C5[o] = a5[i];
  }
}

// ---------------------------------------------------------------------------
// Kernel 3: scan. 1 block/batch, 512 threads = 8 waves (wj = w&1, wn = w>>1).
// Per wave: j-tiles 4 (64 j), n-tiles 2 (32 n). MFMA 16x16x32 bf16, h as
// hi+lo bf16 stored in MFMA-B-fragment order (lane-linear ds_read_b128).
// W2d/W3d in per-lane VGPRs; W4b^T/W5b^T bf16 in LDS; 3 barriers/step.
// ---------------------------------------------------------------------------
__global__ __launch_bounds__(512, 2)
void k_scan(const int* __restrict__ qs,
            const float* __restrict__ qmat,
            const float* __restrict__ h0,
            const float* __restrict__ K2, const float* __restrict__ K3,
            const float* __restrict__ C4, const float* __restrict__ C5,
            const float* __restrict__ W2, const float* __restrict__ W3,
            const float* __restrict__ W4, const float* __restrict__ W5,
            float* __restrict__ out) {
  const int b   = blockIdx.x;
  const int tid = threadIdx.x;
  const int w   = tid >> 6;
  const int l   = tid & 63;
  const int l15 = l & 15;
  const int g   = l >> 4;
  const int wj  = w & 1;
  const int wn  = w >> 1;          // 0..3
  const int gc  = 16 * w + l15;    // GEMV output column
  const int kb  = 32 * g;          // GEMV contraction base

  __shared__ alignas(16) unsigned short hBH[16384];   // h hi bf16, frag order
  __shared__ alignas(16) unsigned short hBL[16384];   // h lo bf16, frag order
  __shared__ alignas(16) unsigned short W4T[DK * 136]; // W4b^T bf16, row stride 136
  __shared__ alignas(16) unsigned short W5T[DK * 136]; // W5b^T bf16
  __shared__ alignas(16) float sLG[144], sV[144];
  __shared__ alignas(16) float sHTp[4][144];           // h_tilde partials per wn
  __shared__ alignas(16) float sQ[2][DK];
  __shared__ float sY[8];

  const float* W2d = W2 + 3 * DK * DK;
  const float* W3d = W3 + 3 * DK * DK;
  const float* W4a = W4;
  const float* W4b = W4 + DK * DK;
  const float* W5b = W5 + DK * DK;

  // ---- per-lane f32 weight registers for A1
  float w2r[32], w3r[32];
#pragma unroll
  for (int kk = 0; kk < 32; ++kk) {
    w2r[kk] = W2d[(kb + kk) * DK + gc];
    w3r[kk] = W3d[(kb + kk) * DK + gc];
  }

  // ---- W4b^T / W5b^T bf16 into LDS (one-time)
  for (int i = tid; i < DK * DK; i += 512) {
    int k = i >> 7, j = i & 127;
    W4T[j * 136 + k] = f2bf(W4b[i]);
    W5T[j * 136 + k] = f2bf(W5b[i]);
  }

  // ---- A-fragments: A = W4a^T (bf16), afr[jt][ks]
  bf16x8 afr[4][4];
#pragma unroll
  for (int jt = 0; jt < 4; ++jt) {
    int j = 64 * wj + 16 * jt + l15;
#pragma unroll
    for (int ks = 0; ks < 4; ++ks) {
      bf16x8 v;
#pragma unroll
      for (int e = 0; e < 8; ++e) v[e] = (short)f2bf(W4a[(ks * 32 + g * 8 + e) * DK + j]);
      afr[jt][ks] = v;
    }
  }

  if (tid < DK) sQ[0][tid] = (tid < NC) ? qmat[qs[b * S] * NC + tid] : 0.0f;
  if (tid == 0) out[b * S] = 0.0f;

  // ---- init h registers + fragment-order bf16 LDS
  float hold[4][2][4];
#pragma unroll
  for (int jt = 0; jt < 4; ++jt) {
    int j4 = 64 * wj + 16 * jt + 4 * g;
    int ks = j4 >> 5, lg = (j4 >> 3) & 3;
#pragma unroll
    for (int nt = 0; nt < 2; ++nt) {
      int ntg = 2 * wn + nt;
      int n = 16 * ntg + l15;
      ushort4 vh, vl;
#pragma unroll
      for (int r = 0; r < 4; ++r) {
        float x = (n < NC) ? h0[n * DK + j4 + r] : 0.0f;
        hold[jt][nt][r] = x;
        unsigned u = __float_as_uint(x);
        ((unsigned short*)&vh)[r] = (unsigned short)(u >> 16);
        float lo = x - __uint_as_float(u & 0xffff0000u);
        ((unsigned short*)&vl)[r] = (unsigned short)(__float_as_uint(lo) >> 16);
      }
      int idx = ((ntg * 4 + ks) * 64 + (lg << 4) + l15) * 8 + ((j4 & 4) ? 4 : 0);
      *(ushort4*)&hBH[idx] = vh;
      *(ushort4*)&hBL[idx] = vl;
    }
  }
  __syncthreads();

  // ---- h_tilde0 partials
  {
    float htp[4][4] = {};
#pragma unroll
    for (int jt = 0; jt < 4; ++jt)
#pragma unroll
      for (int nt = 0; nt < 2; ++nt) {
        int n = 16 * (2 * wn + nt) + l15;
        float qe = sQ[0][n];
#pragma unroll
        for (int r = 0; r < 4; ++r) htp[jt][r] = fmaf(qe, hold[jt][nt][r], htp[jt][r]);
      }
#pragma unroll
    for (int jt = 0; jt < 4; ++jt)
#pragma unroll
      for (int r = 0; r < 4; ++r) {
        float v = htp[jt][r];
        v += __shfl_xor(v, 1, 64); v += __shfl_xor(v, 2, 64);
        v += __shfl_xor(v, 4, 64); v += __shfl_xor(v, 8, 64);
        htp[jt][r] = v;
      }
    if (l15 == 0) {
#pragma unroll
      for (int jt = 0; jt < 4; ++jt) {
        int jj = 64 * wj + 16 * jt + 4 * g;
#pragma unroll
        for (int r = 0; r < 4; ++r) sHTp[wn][pk(jj) + r] = htp[jt][r];
      }
    }
  }
  __syncthreads();

  for (int t = 0; t < T; ++t) {
    const int cur = t & 1, nxt = cur ^ 1;
    const int bt = (b * T + t) * DK;

    // prefetch step constants (global; overlap with M/A1)
    float k2v = K2[bt + gc], k3v = K3[bt + gc];
    float c4v = C4[bt + gc], c5v = C5[bt + gc];
    float qnew = 0.0f;
    if (tid < DK) qnew = (tid < NC) ? qmat[qs[b * S + t + 1] * NC + tid] : 0.0f;

    // ---- Phase M: dot = W4a^T x h^T (hi+lo), fragment-linear LDS reads
    f32x4 acc[4][2];
#pragma unroll
    for (int jt = 0; jt < 4; ++jt) {
      acc[jt][0] = (f32x4){0.f, 0.f, 0.f, 0.f};
      acc[jt][1] = (f32x4){0.f, 0.f, 0.f, 0.f};
    }
#pragma unroll
    for (int nt = 0; nt < 2; ++nt) {
      int ntg = 2 * wn + nt;
      if (ntg == 7) continue;                        // padded tile, stays zero
#pragma unroll
      for (int ks = 0; ks < 4; ++ks) {
        bf16x8 bh = *(const bf16x8*)&hBH[(ntg * 4 + ks) * 512 + l * 8];
        bf16x8 bl = *(const bf16x8*)&hBL[(ntg * 4 + ks) * 512 + l * 8];
#pragma unroll
        for (int jt = 0; jt < 4; ++jt) {
          acc[jt][nt] = __builtin_amdgcn_mfma_f32_16x16x32_bf16(afr[jt][ks], bh, acc[jt][nt], 0, 0, 0);
          acc[jt][nt] = __builtin_amdgcn_mfma_f32_16x16x32_bf16(afr[jt][ks], bl, acc[jt][nt], 0, 0, 0);
        }
      }
    }

    // ---- Phase A1: x2/x3 = K2/K3 + h_tilde@W2d/W3d (weights in VGPRs)
    {
      float p2 = 0.f, p3 = 0.f;
#pragma unroll
      for (int m = 0; m < 8; ++m) {
        int base = 36 * g + 4 * m;
        float4 s0 = *(const float4*)&sHTp[0][base];
        float4 s1 = *(const float4*)&sHTp[1][base];
        float4 s2 = *(const float4*)&sHTp[2][base];
        float4 s3 = *(const float4*)&sHTp[3][base];
        float sx = s0.x + s1.x + s2.x + s3.x;
        float sy = s0.y + s1.y + s2.y + s3.y;
        float sz = s0.z + s1.z + s2.z + s3.z;
        float sw = s0.w + s1.w + s2.w + s3.w;
        p2 = fmaf(sx, w2r[4 * m + 0], p2); p3 = fmaf(sx, w3r[4 * m + 0], p3);
        p2 = fmaf(sy, w2r[4 * m + 1], p2); p3 = fmaf(sy, w3r[4 * m + 1], p3);
        p2 = fmaf(sz, w2r[4 * m + 2], p2); p3 = fmaf(sz, w3r[4 * m + 2], p3);
        p2 = fmaf(sw, w2r[4 * m + 3], p2); p3 = fmaf(sw, w3r[4 * m + 3], p3);
      }
      p2 += __shfl_xor(p2, 16, 64); p2 += __shfl_xor(p2, 32, 64);
      p3 += __shfl_xor(p3, 16, 64); p3 += __shfl_xor(p3, 32, 64);
      if (l < 16) {
        float x2 = k2v + p2, x3 = k3v + p3;
        sLG[pk(gc)] = sigm(x3) * (tanh_fast(x2) + 1.0f) * 0.5f;
      }
    }
    if (tid < DK) sQ[nxt][tid] = qnew;
    __syncthreads();                                  // b1

    // deferred y-write of previous step (sY ordered by b1)
    if (t > 0 && tid == 0) {
      float s = sY[0] + sY[1] + sY[2] + sY[3] + sY[4] + sY[5] + sY[6] + sY[7];
      out[b * S + t] = s * (1.0f / DK);
    }

    // ---- Phase A2: V = C4 + LG @ W4b (bf16 weights from LDS)
    {
      float pa = 0.f;
#pragma unroll
      for (int mm = 0; mm < 4; ++mm) {
        u16x8 wv = *(const u16x8*)&W4T[gc * 136 + kb + 8 * mm];
        float4 a0 = *(const float4*)&sLG[36 * g + 8 * mm];
        float4 a1 = *(const float4*)&sLG[36 * g + 8 * mm + 4];
        pa = fmaf(a0.x, __uint_as_float(((unsigned)wv[0]) << 16), pa);
        pa = fmaf(a0.y, __uint_as_float(((unsigned)wv[1]) << 16), pa);
        pa = fmaf(a0.z, __uint_as_float(((unsigned)wv[2]) << 16), pa);
        pa = fmaf(a0.w, __uint_as_float(((unsigned)wv[3]) << 16), pa);
        pa = fmaf(a1.x, __uint_as_float(((unsigned)wv[4]) << 16), pa);
        pa = fmaf(a1.y, __uint_as_float(((unsigned)wv[5]) << 16), pa);
        pa = fmaf(a1.z, __uint_as_float(((unsigned)wv[6]) << 16), pa);
        pa = fmaf(a1.w, __uint_as_float(((unsigned)wv[7]) << 16), pa);
      }
      pa += __shfl_xor(pa, 16, 64); pa += __shfl_xor(pa, 32, 64);
      if (l < 16) sV[pk(gc)] = c4v + pa;
    }
    __syncthreads();                                  // b2

    // ---- Phase B2: gamma_f, h update (regs), frag writeback, h_tilde partials
    {
#pragma unroll
      for (int jt = 0; jt < 4; ++jt) {
        int j4 = 64 * wj + 16 * jt + 4 * g;
        int pj = pk(j4);
        float4 a = *(const float4*)&sLG[pj];
        float4 c = *(const float4*)&sV[pj];
        float lgv[4] = {a.x, a.y, a.z, a.w};
        float vv[4]  = {c.x, c.y, c.z, c.w};
        float htpr[4] = {0.f, 0.f, 0.f, 0.f};
        int ks = j4 >> 5, lg = (j4 >> 3) & 3;
#pragma unroll
        for (int nt = 0; nt < 2; ++nt) {
          int ntg = 2 * wn + nt;
          if (ntg == 7) continue;
          int n = 16 * ntg + l15;
          float qe = sQ[cur][n], qn = sQ[nxt][n];
          ushort4 vh, vl;
#pragma unroll
          for (int r = 0; r < 4; ++r) {
            float gf = sigm(acc[jt][nt][r] + vv[r]);
            float hn = fmaf(gf, hold[jt][nt][r], qe * lgv[r]);
            hold[jt][nt][r] = hn;
            htpr[r] = fmaf(qn, hn, htpr[r]);
            unsigned u = __float_as_uint(hn);
            ((unsigned short*)&vh)[r] = (unsigned short)(u >> 16);
            float lo = hn - __uint_as_float(u & 0xffff0000u);
            ((unsigned short*)&vl)[r] = (unsigned short)(__float_as_uint(lo) >> 16);
          }
          int idx = ((ntg * 4 + ks) * 64 + (lg << 4) + l15) * 8 + ((j4 & 4) ? 4 : 0);
          *(ushort4*)&hBH[idx] = vh;
          *(ushort4*)&hBL[idx] = vl;
        }
#pragma unroll
        for (int r = 0; r < 4; ++r) {
          float v = htpr[r];
          v += __shfl_xor(v, 1, 64); v += __shfl_xor(v, 2, 64);
          v += __shfl_xor(v, 4, 64); v += __shfl_xor(v, 8, 64);
          htpr[r] = v;
        }
        if (l15 == 0) {
#pragma unroll
          for (int r = 0; r < 4; ++r) sHTp[wn][pk(j4) + r] = htpr[r];
        }
      }
    }
    __syncthreads();                                  // b3

    // ---- Phase C: y = mean(sigmoid(C5 + h_tilde @ W5b))
    {
      float pc = 0.f;
#pragma unroll
      for (int mm = 0; mm < 4; ++mm) {
        u16x8 wv = *(const u16x8*)&W5T[gc * 136 + kb + 8 * mm];
        int base = 36 * g + 8 * mm;
        float4 s0a = *(const float4*)&sHTp[0][base];
        float4 s1a = *(const float4*)&sHTp[1][base];
        float4 s2a = *(const float4*)&sHTp[2][base];
        float4 s3a = *(const float4*)&sHTp[3][base];
        float4 s0b = *(const float4*)&sHTp[0][base + 4];
        float4 s1b = *(const float4*)&sHTp[1][base + 4];
        float4 s2b = *(const float4*)&sHTp[2][base + 4];
        float4 s3b = *(const float4*)&sHTp[3][base + 4];
        float h0v = s0a.x + s1a.x + s2a.x + s3a.x;
        float h1v = s0a.y + s1a.y + s2a.y + s3a.y;
        float h2v = s0a.z + s1a.z + s2a.z + s3a.z;
        float h3v = s0a.w + s1a.w + s2a.w + s3a.w;
        float h4v = s0b.x + s1b.x + s2b.x + s3b.x;
        float h5v = s0b.y + s1b.y + s2b.y + s3b.y;
        float h6v = s0b.z + s1b.z + s2b.z + s3b.z;
        float h7v = s0b.w + s1b.w + s2b.w + s3b.w;
        pc = fmaf(h0v, __uint_as_float(((unsigned)wv[0]) << 16), pc);
        pc = fmaf(h1v, __uint_as_float(((unsigned)wv[1]) << 16), pc);
        pc = fmaf(h2v, __uint_as_float(((unsigned)wv[2]) << 16), pc);
        pc = fmaf(h3v, __uint_as_float(((unsigned)wv[3]) << 16), pc);
        pc = fmaf(h4v, __uint_as_float(((unsigned)wv[4]) << 16), pc);
        pc = fmaf(h5v, __uint_as_float(((unsigned)wv[5]) << 16), pc);
        pc = fmaf(h6v, __uint_as_float(((unsigned)wv[6]) << 16), pc);
        pc = fmaf(h7v, __uint_as_float(((unsigned)wv[7]) << 16), pc);
      }
      pc += __shfl_xor(pc, 16, 64); pc += __shfl_xor(pc, 32, 64);
      float u = sigm(c5v + pc);
      u += __shfl_xor(u, 1, 64); u += __shfl_xor(u, 2, 64);
      u += __shfl_xor(u, 4, 64); u += __shfl_xor(u, 8, 64);
      if (l == 0) sY[w] = u;
    }
    // no barrier: sY/sHTp consumed after next b1 / protected by b3 ordering
  }
  __syncthreads();
  if (tid == 0) {
    float s = sY[0] + sY[1] + sY[2] + sY[3] + sY[4] + sY[5] + sY[6] + sY[7];
    out[b * S + T] = s * (1.0f / DK);
  }
}

extern "C" void kernel_launch(void* const* d_in, const int* in_sizes, int n_in,
                              void* d_out, int out_size, void* d_ws, size_t ws_size,
                              hipStream_t stream) {
  const int*   qs   = (const int*)d_in[0];
  const int*   ats  = (const int*)d_in[1];
  const int*   its  = (const int*)d_in[2];
  const float* corr = (const float*)d_in[3];
  const float* qmat = (const float*)d_in[4];
  const float* h0   = (const float*)d_in[5];
  const float* e_w  = (const float*)d_in[6];
  const float* at_w = (const float*)d_in[7];
  const float* it_w = (const float*)d_in[8];
  const float* W1 = (const float*)d_in[9];  const float* b1 = (const float*)d_in[10];
  const float* W2 = (const float*)d_in[11]; const float* b2 = (const float*)d_in[12];
  const float* W3 = (const float*)d_in[13]; const float* b3 = (const float*)d_in[14];
  const float* W4 = (const float*)d_in[15]; const float* b4 = (const float*)d_in[16];
  const float* W5 = (const float*)d_in[17]; const float* b5 = (const float*)d_in[18];
  float* out = (float*)d_out;

  float* AL = (float*)d_ws;              // B*S*DK
  float* K2 = AL + B * S * DK;           // B*T*DK
  float* K3 = K2 + B * T * DK;
  float* C4 = K3 + B * T * DK;
  float* C5 = C4 + B * T * DK;

  k_all_learning<<<dim3(B * 16), dim3(DK), 0, stream>>>(qs, ats, corr, e_w, at_w, W1, b1, AL);
  k_consts<<<dim3(B * 16), dim3(DK), 0, stream>>>(qs, its, it_w, e_w, AL,
                                                  W2, b2, W3, b3, W4, b4, W5, b5,
                                                  K2, K3, C4, C5);
  k_scan<<<dim3(B), dim3(512), 0, stream>>>(qs, qmat, h0, K2, K3, C4, C5,
                                            W2, W3, W4, W5, out);
}